// Round 12
// baseline (461.231 us; speedup 1.0000x reference)
//
#include <hip/hip_runtime.h>
#include <hip/hip_bf16.h>
#include <stdint.h>

#define D_MODEL 1024
#define NHEADS  16
#define DK      64
#define TSEQ    2048
#define BATCH   4
#define MROWS   8192   // B*T

typedef __attribute__((ext_vector_type(8))) short bf16x8;
typedef __attribute__((ext_vector_type(4))) float f32x4;
typedef __attribute__((ext_vector_type(16))) float f32x16;

__device__ __forceinline__ void gl_lds16(const void* g, void* l) {
  __builtin_amdgcn_global_load_lds(
      (const __attribute__((address_space(1))) unsigned int*)g,
      (__attribute__((address_space(3))) unsigned int*)l,
      16, 0, 0);
}

__device__ __forceinline__ short f2bs(float f) {
  union { __hip_bfloat16 h; short s; } u;
  u.h = __float2bfloat16(f);
  return u.s;
}

// packed f32->bf16 pair conversion. s_nop 1 guards the TRANS(v_exp)->read
// hazard (hazard recognizer does not insert waits for INLINEASM consumers).
__device__ __forceinline__ uint32_t cvt_pk(float lo, float hi) {
  uint32_t r;
  asm("s_nop 1\n\tv_cvt_pk_bf16_f32 %0, %1, %2" : "=v"(r) : "v"(lo), "v"(hi));
  return r;
}

// v_permlane32_swap_b32: a' = {a_lo, b_lo}, b' = {a_hi, b_hi}
__device__ __forceinline__ void permswap(uint32_t& a, uint32_t& b) {
  asm("v_permlane32_swap_b32 %0, %1" : "+v"(a), "+v"(b));
}

// ---------------- cast x (fp32 -> bf16), vectorized ----------------
__global__ void cast_x_kernel(const float* __restrict__ in, short* __restrict__ out, int n4) {
  int i = blockIdx.x * blockDim.x + threadIdx.x;
  if (i >= n4) return;
  const float4 v = reinterpret_cast<const float4*>(in)[i];
  short4 r;
  r.x = f2bs(v.x); r.y = f2bs(v.y); r.z = f2bs(v.z); r.w = f2bs(v.w);
  reinterpret_cast<short4*>(out)[i] = r;
}

// ---------------- transpose + cast W: dst[n][k] = src[k][n] (1024x1024) ----------------
__global__ void transpose_cast_kernel(const float* __restrict__ src, short* __restrict__ dst) {
  __shared__ float tile[32][33];
  const int tx = threadIdx.x, ty = threadIdx.y;
  const int n0 = blockIdx.x * 32, k0 = blockIdx.y * 32;
#pragma unroll
  for (int r = 0; r < 32; r += 8)
    tile[ty + r][tx] = src[(size_t)(k0 + ty + r) * D_MODEL + n0 + tx];
  __syncthreads();
#pragma unroll
  for (int r = 0; r < 32; r += 8)
    dst[(size_t)(n0 + ty + r) * D_MODEL + k0 + tx] = f2bs(tile[tx][ty + r]);
}

// ---------------- GEMM main-loop: 2-phase double-buffered stage-ahead ----------------
#define GEMM_MAIN_LOOP(A_, BT_)                                                     \
  __shared__ short SM[2][8192];                                                     \
  const int tid = threadIdx.x;                                                      \
  const int lane = tid & 63;                                                        \
  const int w = tid >> 6;                                                           \
  const int wm = w >> 1, wn = w & 1;                                                \
  const int rowBase = blockIdx.x * 128;                                             \
  const int colBase = blockIdx.y * 128;                                             \
  const int g = lane >> 4;                                                          \
  const int c15 = lane & 15;                                                        \
  f32x4 acc[4][4];                                                                  \
  _Pragma("unroll")                                                                 \
  for (int i = 0; i < 4; ++i)                                                       \
    _Pragma("unroll")                                                               \
    for (int j = 0; j < 4; ++j) acc[i][j] = {0.f, 0.f, 0.f, 0.f};                   \
  const int schunk = (lane & 3) ^ ((lane >> 2) & 3) ^ ((lane >> 4) & 3);            \
  const short* gA = (A_) + (size_t)(rowBase + w * 16 + (lane >> 2)) * 1024 + schunk * 8; \
  const short* gB = (BT_) + (size_t)(colBase + w * 16 + (lane >> 2)) * 1024 + schunk * 8; \
  const int ko = (g ^ (c15 & 3) ^ (c15 >> 2)) * 8;                                  \
  _Pragma("unroll")                                                                 \
  for (int c = 0; c < 2; ++c) {                                                     \
    gl_lds16(gA + (size_t)(c * 64) * 1024, &SM[0][w * 512 + c * 2048]);             \
    gl_lds16(gB + (size_t)(c * 64) * 1024, &SM[0][4096 + w * 512 + c * 2048]);      \
  }                                                                                 \
  _Pragma("unroll 2")                                                               \
  for (int kt = 0; kt < 1024; kt += 32) {                                           \
    const int buf = (kt >> 5) & 1;                                                  \
    asm volatile("s_waitcnt vmcnt(0)" ::: "memory");                                \
    __builtin_amdgcn_s_barrier();                                                   \
    __builtin_amdgcn_sched_barrier(0);                                              \
    if (kt + 32 < 1024) {                                                           \
      _Pragma("unroll")                                                             \
      for (int c = 0; c < 2; ++c) {                                                 \
        gl_lds16(gA + (size_t)(c * 64) * 1024 + kt + 32, &SM[buf ^ 1][w * 512 + c * 2048]); \
        gl_lds16(gB + (size_t)(c * 64) * 1024 + kt + 32, &SM[buf ^ 1][4096 + w * 512 + c * 2048]); \
      }                                                                             \
    }                                                                               \
    const short* smA = &SM[buf][0];                                                 \
    const short* smB = &SM[buf][4096];                                              \
    bf16x8 af[4], bfr[4];                                                           \
    _Pragma("unroll")                                                               \
    for (int i = 0; i < 4; ++i)                                                     \
      af[i] = *reinterpret_cast<const bf16x8*>(&smA[(wm * 64 + i * 16 + c15) * 32 + ko]); \
    _Pragma("unroll")                                                               \
    for (int j = 0; j < 4; ++j)                                                     \
      bfr[j] = *reinterpret_cast<const bf16x8*>(&smB[(wn * 64 + j * 16 + c15) * 32 + ko]); \
    __builtin_amdgcn_s_setprio(1);                                                  \
    _Pragma("unroll")                                                               \
    for (int i = 0; i < 4; ++i)                                                     \
      _Pragma("unroll")                                                             \
      for (int j = 0; j < 4; ++j)                                                   \
        acc[i][j] = __builtin_amdgcn_mfma_f32_16x16x32_bf16(af[i], bfr[j], acc[i][j], 0, 0, 0); \
    __builtin_amdgcn_s_setprio(0);                                                  \
  }                                                                                 \
  __syncthreads();

// ---------------- fused QKV projection: C[8192,3072], scatter per sub-matrix ----
__global__ __launch_bounds__(256, 2) void gemm_qkv_kernel(
    const short* __restrict__ A, const short* __restrict__ BTm,
    const float* __restrict__ bq, const float* __restrict__ bk,
    const float* __restrict__ bv, short* __restrict__ Qb,
    short* __restrict__ Kb, short* __restrict__ Vtb, float CL) {
  GEMM_MAIN_LOOP(A, BTm)
  const int mat = colBase >> 10;                       // uniform per block
  if (mat == 2) {
    // scatter acc -> LDS [d][t ^ ((d&15)<<3)] (pairs packed via cvt_pk)
    short* smf = &SM[0][0];                            // 16384 shorts = 128x128
    const int d_base = wn * 64 + c15;
#pragma unroll
    for (int j = 0; j < 4; ++j) {
      const int dl = d_base + j * 16;
      const int gcol = (colBase & 1023) + dl;
      const float bb = bv[gcol];
      const int sw = (dl & 15) << 3;
#pragma unroll
      for (int i = 0; i < 4; ++i) {
        const int tb = wm * 64 + i * 16 + g * 4;
#pragma unroll
        for (int r = 0; r < 4; r += 2) {
          const uint32_t p = cvt_pk(acc[i][j][r] + bb, acc[i][j][r + 1] + bb);
          *reinterpret_cast<uint32_t*>(&smf[dl * 128 + ((tb + r) ^ sw)]) = p;
        }
      }
    }
    __syncthreads();
    const int b0 = rowBase >> 11, t0 = rowBase & 2047;
    const int vcolBase = colBase & 1023;
#pragma unroll
    for (int k = 0; k < 8; ++k) {
      const int cid = k * 256 + tid;                   // 2048 chunks of 8 shorts
      const int d = cid >> 4;
      const int c = cid & 15;
      const bf16x8 vv = *reinterpret_cast<const bf16x8*>(
          &smf[d * 128 + ((c * 8) ^ ((d & 15) << 3))]);
      *reinterpret_cast<bf16x8*>(
          &Vtb[((size_t)(b0 * 1024 + vcolBase + d)) * 2048 + t0 + c * 8]) = vv;
    }
  } else {
    const float* bp = (mat == 0) ? bq : bk;
    const float scl = (mat == 0) ? CL : 1.0f;
    short* Ob = (mat == 0) ? Qb : Kb;
#pragma unroll
    for (int i = 0; i < 4; ++i) {
#pragma unroll
      for (int j = 0; j < 4; ++j) {
#pragma unroll
        for (int r = 0; r < 4; ++r) {
          const int grow = rowBase + wm * 64 + i * 16 + g * 4 + r;
          const int gcol = (colBase + wn * 64 + j * 16 + c15) & 1023;
          const float v = (acc[i][j][r] + bp[gcol]) * scl;
          const int b = grow >> 11, t = grow & 2047;
          const int h = gcol >> 6, d = gcol & 63;
          Ob[((size_t)(b * NHEADS + h) * TSEQ + t) * DK + d] = f2bs(v);
        }
      }
    }
  }
}

// ---------------- output projection: fp32 [M,N] ----------------
__global__ __launch_bounds__(256, 2) void gemm_out_kernel(
    const short* __restrict__ A, const short* __restrict__ BTm,
    const float* __restrict__ bias, float* __restrict__ Cout) {
  GEMM_MAIN_LOOP(A, BTm)
#pragma unroll
  for (int i = 0; i < 4; ++i) {
#pragma unroll
    for (int j = 0; j < 4; ++j) {
#pragma unroll
      for (int r = 0; r < 4; ++r) {
        const int grow = rowBase + wm * 64 + i * 16 + g * 4 + r;
        const int gcol = colBase + wn * 64 + j * 16 + c15;
        Cout[(size_t)grow * 1024 + gcol] = acc[i][j][r] + bias[gcol];
      }
    }
  }
}

// ---------------- flash attention v8 ----------------
// v7 + XCD-aware 1D grid decode: all 16 q-tiles of one bh land on one XCD
// (lid&7 = XCD under round-robin dispatch), so each bh's K/V is fetched from
// HBM by exactly one XCD's L2 (8 bh x 512KB = 4MB = one L2). 5 blocks/CU.
__global__ __launch_bounds__(256, 5) void attn_kernel(
    const short* __restrict__ Qg, const short* __restrict__ Kg,
    const short* __restrict__ Vtg, short* __restrict__ ctx) {
  __shared__ short Ks[2][64 * 64];
  __shared__ short VTs[2][64 * 64];

  const int tid = threadIdx.x;
  const int lane = tid & 63;
  const int w = tid >> 6;
  const int l5 = lane >> 5;
  const int c31 = lane & 31;
  // XCD-aware decode of 1D block id (bijective on [0,1024))
  const int lid = blockIdx.x;
  const int bh = (lid >> 7) * 8 + (lid & 7);
  const int qbase = ((lid >> 3) & 15) * 128;
  const int b = bh >> 4, h = bh & 15;

  const short* Qp = Qg + (size_t)bh * TSEQ * DK;
  const short* Kp = Kg + (size_t)bh * TSEQ * DK;
  const short* Vtp = Vtg + (size_t)bh * DK * TSEQ;

  const int qrow = qbase + w * 32 + c31;

  bf16x8 qf[4];
#pragma unroll
  for (int kd = 0; kd < 4; ++kd)
    qf[kd] = *reinterpret_cast<const bf16x8*>(Qp + (size_t)qrow * DK + kd * 16 + l5 * 8);

  f32x16 o0, o1;
#pragma unroll
  for (int r = 0; r < 16; ++r) { o0[r] = 0.f; o1[r] = 0.f; }
  float l_s = 0.f;

  f32x16 z16;
#pragma unroll
  for (int r = 0; r < 16; ++r) z16[r] = 0.f;

  const int srow = w * 8 + (lane >> 3);
  const int soff = ((lane & 7) ^ (lane >> 3) ^ (w & 3)) * 8;
  const int swz = (((c31 & 7) ^ (c31 >> 3)) << 4);

  int offA[4];
#pragma unroll
  for (int kd = 0; kd < 4; ++kd)
    offA[kd] = c31 * 64 + ((((kd * 32 + l5 * 16)) ^ swz) >> 1);

#define STAGE(T, SLOT) do {                                                          \
    const int kt_ = (T) * 64;                                                        \
    _Pragma("unroll")                                                                \
    for (int c = 0; c < 2; ++c) {                                                    \
      const int row_ = c * 32 + srow;                                                \
      gl_lds16(Kp + (size_t)(kt_ + row_) * DK + soff, &Ks[SLOT][(c * 4 + w) * 512]); \
      gl_lds16(Vtp + (size_t)row_ * TSEQ + kt_ + soff, &VTs[SLOT][(c * 4 + w) * 512]); \
    }                                                                                \
  } while (0)

#define BODY(T, SLOT, PREFETCH) do {                                                 \
    asm volatile("s_waitcnt vmcnt(0)" ::: "memory");                                 \
    __builtin_amdgcn_s_barrier();                                                    \
    __builtin_amdgcn_sched_barrier(0);                                               \
    if (PREFETCH) STAGE((T) + 1, (SLOT) ^ 1);                                        \
    const short* ksb = &Ks[SLOT][0];                                                 \
    const short* vtb = &VTs[SLOT][0];                                                \
    __builtin_amdgcn_s_setprio(1);                                                   \
    const bf16x8 kf0a = *reinterpret_cast<const bf16x8*>(ksb + offA[0]);             \
    const bf16x8 kf1a = *reinterpret_cast<const bf16x8*>(ksb + 2048 + offA[0]);      \
    f32x16 s0 = __builtin_amdgcn_mfma_f32_32x32x16_bf16(kf0a, qf[0], z16, 0, 0, 0);  \
    f32x16 s1 = __builtin_amdgcn_mfma_f32_32x32x16_bf16(kf1a, qf[0], z16, 0, 0, 0);  \
    _Pragma("unroll")                                                                \
    for (int kd = 1; kd < 4; ++kd) {                                                 \
      const bf16x8 kf0 = *reinterpret_cast<const bf16x8*>(ksb + offA[kd]);           \
      const bf16x8 kf1 = *reinterpret_cast<const bf16x8*>(ksb + 2048 + offA[kd]);    \
      s0 = __builtin_amdgcn_mfma_f32_32x32x16_bf16(kf0, qf[kd], s0, 0, 0, 0);        \
      s1 = __builtin_amdgcn_mfma_f32_32x32x16_bf16(kf1, qf[kd], s1, 0, 0, 0);        \
    }                                                                                \
    __builtin_amdgcn_s_setprio(0);                                                   \
    float p0 = 0.f, p1 = 0.f, p2 = 0.f, p3 = 0.f;                                    \
    _Pragma("unroll")                                                                \
    for (int r = 0; r < 16; r += 4) {                                                \
      s0[r] = __builtin_amdgcn_exp2f(s0[r]);                                         \
      s0[r + 1] = __builtin_amdgcn_exp2f(s0[r + 1]);                                 \
      s0[r + 2] = __builtin_amdgcn_exp2f(s0[r + 2]);                                 \
      s0[r + 3] = __builtin_amdgcn_exp2f(s0[r + 3]);                                 \
      p0 += s0[r]; p1 += s0[r + 1]; p2 += s0[r + 2]; p3 += s0[r + 3];                \
    }                                                                                \
    _Pragma("unroll")                                                                \
    for (int r = 0; r < 16; r += 4) {                                                \
      s1[r] = __builtin_amdgcn_exp2f(s1[r]);                                         \
      s1[r + 1] = __builtin_amdgcn_exp2f(s1[r + 1]);                                 \
      s1[r + 2] = __builtin_amdgcn_exp2f(s1[r + 2]);                                 \
      s1[r + 3] = __builtin_amdgcn_exp2f(s1[r + 3]);                                 \
      p0 += s1[r]; p1 += s1[r + 1]; p2 += s1[r + 2]; p3 += s1[r + 3];                \
    }                                                                                \
    l_s += (p0 + p1) + (p2 + p3);                                                    \
    uint32_t wa[8], wb[8];                                                           \
    _Pragma("unroll")                                                                \
    for (int t2 = 0; t2 < 8; ++t2) {                                                 \
      wa[t2] = cvt_pk(s0[2 * t2], s0[2 * t2 + 1]);                                   \
      wb[t2] = cvt_pk(s1[2 * t2], s1[2 * t2 + 1]);                                   \
    }                                                                                \
    permswap(wa[0], wa[2]); permswap(wa[1], wa[3]);                                  \
    permswap(wa[4], wa[6]); permswap(wa[5], wa[7]);                                  \
    permswap(wb[0], wb[2]); permswap(wb[1], wb[3]);                                  \
    permswap(wb[4], wb[6]); permswap(wb[5], wb[7]);                                  \
    bf16x8 pf[4];                                                                    \
    {                                                                                \
      union { uint32_t u[4]; bf16x8 v; } fr;                                         \
      fr.u[0] = wa[0]; fr.u[1] = wa[1]; fr.u[2] = wa[2]; fr.u[3] = wa[3]; pf[0] = fr.v; \
      fr.u[0] = wa[4]; fr.u[1] = wa[5]; fr.u[2] = wa[6]; fr.u[3] = wa[7]; pf[1] = fr.v; \
      fr.u[0] = wb[0]; fr.u[1] = wb[1]; fr.u[2] = wb[2]; fr.u[3] = wb[3]; pf[2] = fr.v; \
      fr.u[0] = wb[4]; fr.u[1] = wb[5]; fr.u[2] = wb[6]; fr.u[3] = wb[7]; pf[3] = fr.v; \
    }                                                                                \
    __builtin_amdgcn_s_setprio(1);                                                   \
    _Pragma("unroll")                                                                \
    for (int ks = 0; ks < 4; ++ks) {                                                 \
      const bf16x8 vf0 = *reinterpret_cast<const bf16x8*>(vtb + offA[ks]);           \
      const bf16x8 vf1 = *reinterpret_cast<const bf16x8*>(vtb + 2048 + offA[ks]);    \
      o0 = __builtin_amdgcn_mfma_f32_32x32x16_bf16(vf0, pf[ks], o0, 0, 0, 0);        \
      o1 = __builtin_amdgcn_mfma_f32_32x32x16_bf16(vf1, pf[ks], o1, 0, 0, 0);        \
    }                                                                                \
    __builtin_amdgcn_s_setprio(0);                                                   \
  } while (0)

  STAGE(0, 0);
  for (int t = 0; t < 30; t += 2) {
    BODY(t, 0, true);
    BODY(t + 1, 1, true);
  }
  BODY(30, 0, true);
  BODY(31, 1, false);

#undef STAGE
#undef BODY

  l_s += __shfl_xor(l_s, 32, 64);

  const float inv = 1.0f / l_s;
  short* crow = ctx + ((size_t)b * TSEQ + qrow) * D_MODEL + h * 64;
#pragma unroll
  for (int r = 0; r < 16; ++r) {
    const int d = (r & 3) + 8 * (r >> 2) + 4 * l5;
    crow[d] = f2bs(o0[r] * inv);
    crow[32 + d] = f2bs(o1[r] * inv);
  }
}

extern "C" void kernel_launch(void* const* d_in, const int* in_sizes, int n_in,
                              void* d_out, int out_size, void* d_ws, size_t ws_size,
                              hipStream_t stream) {
  const float* x  = (const float*)d_in[0];
  const float* Wq = (const float*)d_in[1];
  const float* bq = (const float*)d_in[2];
  const float* Wk = (const float*)d_in[3];
  const float* bk = (const float*)d_in[4];
  const float* Wv = (const float*)d_in[5];
  const float* bv = (const float*)d_in[6];
  const float* Wo = (const float*)d_in[7];
  const float* bo = (const float*)d_in[8];
  float* out = (float*)d_out;

  short* xb   = (short*)d_ws;                       // 8192*1024 bf16 (reused as ctx)
  short* WqT  = xb + (size_t)MROWS * D_MODEL;       // WqT/WkT/WvT contiguous: fused B
  short* WkT  = WqT + (size_t)D_MODEL * D_MODEL;
  short* WvT  = WkT + (size_t)D_MODEL * D_MODEL;
  short* WoT  = WvT + (size_t)D_MODEL * D_MODEL;
  short* Qb   = WoT + (size_t)D_MODEL * D_MODEL;
  short* Kb   = Qb + (size_t)MROWS * D_MODEL;
  short* Vtb  = Kb + (size_t)MROWS * D_MODEL;       // V^T layout [B,H,dk,T]
  short* ctxb = xb;                                 // xb dead after QKV projection

  const float CL = 0.1803368801111204f;             // 0.125 * log2(e), folded into Q

  cast_x_kernel<<<(MROWS * D_MODEL / 4 + 255) / 256, 256, 0, stream>>>(x, xb, MROWS * D_MODEL / 4);
  dim3 tb(32, 8), tg(32, 32);
  transpose_cast_kernel<<<tg, tb, 0, stream>>>(Wq, WqT);
  transpose_cast_kernel<<<tg, tb, 0, stream>>>(Wk, WkT);
  transpose_cast_kernel<<<tg, tb, 0, stream>>>(Wv, WvT);
  transpose_cast_kernel<<<tg, tb, 0, stream>>>(Wo, WoT);

  gemm_qkv_kernel<<<dim3(MROWS / 128, 3 * D_MODEL / 128), 256, 0, stream>>>(
      xb, WqT, bq, bk, bv, Qb, Kb, Vtb, CL);

  attn_kernel<<<1024, 256, 0, stream>>>(Qb, Kb, Vtb, ctxb);

  gemm_out_kernel<<<dim3(MROWS / 128, D_MODEL / 128), 256, 0, stream>>>(ctxb, WoT, bo, out);
}

// Round 13
// 186.255 us; speedup vs baseline: 2.4763x; 2.4763x over previous
//
#include <hip/hip_runtime.h>
#include <hip/hip_bf16.h>
#include <stdint.h>

#define D_MODEL 1024
#define NHEADS  16
#define DK      64
#define TSEQ    2048
#define BATCH   4
#define MROWS   8192   // B*T

typedef __attribute__((ext_vector_type(8))) short bf16x8;
typedef __attribute__((ext_vector_type(4))) float f32x4;
typedef __attribute__((ext_vector_type(16))) float f32x16;

__device__ __forceinline__ void gl_lds16(const void* g, void* l) {
  __builtin_amdgcn_global_load_lds(
      (const __attribute__((address_space(1))) unsigned int*)g,
      (__attribute__((address_space(3))) unsigned int*)l,
      16, 0, 0);
}

__device__ __forceinline__ short f2bs(float f) {
  union { __hip_bfloat16 h; short s; } u;
  u.h = __float2bfloat16(f);
  return u.s;
}

// packed f32->bf16 pair conversion. s_nop 1 guards the TRANS(v_exp)->read
// hazard (hazard recognizer does not insert waits for INLINEASM consumers).
__device__ __forceinline__ uint32_t cvt_pk(float lo, float hi) {
  uint32_t r;
  asm("s_nop 1\n\tv_cvt_pk_bf16_f32 %0, %1, %2" : "=v"(r) : "v"(lo), "v"(hi));
  return r;
}

// v_permlane32_swap_b32: a' = {a_lo, b_lo}, b' = {a_hi, b_hi}
__device__ __forceinline__ void permswap(uint32_t& a, uint32_t& b) {
  asm("v_permlane32_swap_b32 %0, %1" : "+v"(a), "+v"(b));
}

// ---------------- cast x (fp32 -> bf16), vectorized ----------------
__global__ void cast_x_kernel(const float* __restrict__ in, short* __restrict__ out, int n4) {
  int i = blockIdx.x * blockDim.x + threadIdx.x;
  if (i >= n4) return;
  const float4 v = reinterpret_cast<const float4*>(in)[i];
  short4 r;
  r.x = f2bs(v.x); r.y = f2bs(v.y); r.z = f2bs(v.z); r.w = f2bs(v.w);
  reinterpret_cast<short4*>(out)[i] = r;
}

// ---------------- transpose + cast W: dst[n][k] = src[k][n] (1024x1024) ----------------
__global__ void transpose_cast_kernel(const float* __restrict__ src, short* __restrict__ dst) {
  __shared__ float tile[32][33];
  const int tx = threadIdx.x, ty = threadIdx.y;
  const int n0 = blockIdx.x * 32, k0 = blockIdx.y * 32;
#pragma unroll
  for (int r = 0; r < 32; r += 8)
    tile[ty + r][tx] = src[(size_t)(k0 + ty + r) * D_MODEL + n0 + tx];
  __syncthreads();
#pragma unroll
  for (int r = 0; r < 32; r += 8)
    dst[(size_t)(n0 + ty + r) * D_MODEL + k0 + tx] = f2bs(tile[tx][ty + r]);
}

// ---------------- GEMM main-loop: 2-phase double-buffered stage-ahead ----------------
#define GEMM_MAIN_LOOP(A_, BT_)                                                     \
  __shared__ short SM[2][8192];                                                     \
  const int tid = threadIdx.x;                                                      \
  const int lane = tid & 63;                                                        \
  const int w = tid >> 6;                                                           \
  const int wm = w >> 1, wn = w & 1;                                                \
  const int rowBase = blockIdx.x * 128;                                             \
  const int colBase = blockIdx.y * 128;                                             \
  const int g = lane >> 4;                                                          \
  const int c15 = lane & 15;                                                        \
  f32x4 acc[4][4];                                                                  \
  _Pragma("unroll")                                                                 \
  for (int i = 0; i < 4; ++i)                                                       \
    _Pragma("unroll")                                                               \
    for (int j = 0; j < 4; ++j) acc[i][j] = {0.f, 0.f, 0.f, 0.f};                   \
  const int schunk = (lane & 3) ^ ((lane >> 2) & 3) ^ ((lane >> 4) & 3);            \
  const short* gA = (A_) + (size_t)(rowBase + w * 16 + (lane >> 2)) * 1024 + schunk * 8; \
  const short* gB = (BT_) + (size_t)(colBase + w * 16 + (lane >> 2)) * 1024 + schunk * 8; \
  const int ko = (g ^ (c15 & 3) ^ (c15 >> 2)) * 8;                                  \
  _Pragma("unroll")                                                                 \
  for (int c = 0; c < 2; ++c) {                                                     \
    gl_lds16(gA + (size_t)(c * 64) * 1024, &SM[0][w * 512 + c * 2048]);             \
    gl_lds16(gB + (size_t)(c * 64) * 1024, &SM[0][4096 + w * 512 + c * 2048]);      \
  }                                                                                 \
  _Pragma("unroll 2")                                                               \
  for (int kt = 0; kt < 1024; kt += 32) {                                           \
    const int buf = (kt >> 5) & 1;                                                  \
    asm volatile("s_waitcnt vmcnt(0)" ::: "memory");                                \
    __builtin_amdgcn_s_barrier();                                                   \
    __builtin_amdgcn_sched_barrier(0);                                              \
    if (kt + 32 < 1024) {                                                           \
      _Pragma("unroll")                                                             \
      for (int c = 0; c < 2; ++c) {                                                 \
        gl_lds16(gA + (size_t)(c * 64) * 1024 + kt + 32, &SM[buf ^ 1][w * 512 + c * 2048]); \
        gl_lds16(gB + (size_t)(c * 64) * 1024 + kt + 32, &SM[buf ^ 1][4096 + w * 512 + c * 2048]); \
      }                                                                             \
    }                                                                               \
    const short* smA = &SM[buf][0];                                                 \
    const short* smB = &SM[buf][4096];                                              \
    bf16x8 af[4], bfr[4];                                                           \
    _Pragma("unroll")                                                               \
    for (int i = 0; i < 4; ++i)                                                     \
      af[i] = *reinterpret_cast<const bf16x8*>(&smA[(wm * 64 + i * 16 + c15) * 32 + ko]); \
    _Pragma("unroll")                                                               \
    for (int j = 0; j < 4; ++j)                                                     \
      bfr[j] = *reinterpret_cast<const bf16x8*>(&smB[(wn * 64 + j * 16 + c15) * 32 + ko]); \
    __builtin_amdgcn_s_setprio(1);                                                  \
    _Pragma("unroll")                                                               \
    for (int i = 0; i < 4; ++i)                                                     \
      _Pragma("unroll")                                                             \
      for (int j = 0; j < 4; ++j)                                                   \
        acc[i][j] = __builtin_amdgcn_mfma_f32_16x16x32_bf16(af[i], bfr[j], acc[i][j], 0, 0, 0); \
    __builtin_amdgcn_s_setprio(0);                                                  \
  }                                                                                 \
  __syncthreads();

// ---------------- fused QKV projection: C[8192,3072], scatter per sub-matrix ----
__global__ __launch_bounds__(256, 2) void gemm_qkv_kernel(
    const short* __restrict__ A, const short* __restrict__ BTm,
    const float* __restrict__ bq, const float* __restrict__ bk,
    const float* __restrict__ bv, short* __restrict__ Qb,
    short* __restrict__ Kb, short* __restrict__ Vtb, float CL) {
  GEMM_MAIN_LOOP(A, BTm)
  const int mat = colBase >> 10;                       // uniform per block
  if (mat == 2) {
    // scatter acc -> LDS [d][t ^ ((d&15)<<3)] (pairs packed via cvt_pk)
    short* smf = &SM[0][0];                            // 16384 shorts = 128x128
    const int d_base = wn * 64 + c15;
#pragma unroll
    for (int j = 0; j < 4; ++j) {
      const int dl = d_base + j * 16;
      const int gcol = (colBase & 1023) + dl;
      const float bb = bv[gcol];
      const int sw = (dl & 15) << 3;
#pragma unroll
      for (int i = 0; i < 4; ++i) {
        const int tb = wm * 64 + i * 16 + g * 4;
#pragma unroll
        for (int r = 0; r < 4; r += 2) {
          const uint32_t p = cvt_pk(acc[i][j][r] + bb, acc[i][j][r + 1] + bb);
          *reinterpret_cast<uint32_t*>(&smf[dl * 128 + ((tb + r) ^ sw)]) = p;
        }
      }
    }
    __syncthreads();
    const int b0 = rowBase >> 11, t0 = rowBase & 2047;
    const int vcolBase = colBase & 1023;
#pragma unroll
    for (int k = 0; k < 8; ++k) {
      const int cid = k * 256 + tid;                   // 2048 chunks of 8 shorts
      const int d = cid >> 4;
      const int c = cid & 15;
      const bf16x8 vv = *reinterpret_cast<const bf16x8*>(
          &smf[d * 128 + ((c * 8) ^ ((d & 15) << 3))]);
      *reinterpret_cast<bf16x8*>(
          &Vtb[((size_t)(b0 * 1024 + vcolBase + d)) * 2048 + t0 + c * 8]) = vv;
    }
  } else {
    const float* bp = (mat == 0) ? bq : bk;
    const float scl = (mat == 0) ? CL : 1.0f;
    short* Ob = (mat == 0) ? Qb : Kb;
#pragma unroll
    for (int i = 0; i < 4; ++i) {
#pragma unroll
      for (int j = 0; j < 4; ++j) {
#pragma unroll
        for (int r = 0; r < 4; ++r) {
          const int grow = rowBase + wm * 64 + i * 16 + g * 4 + r;
          const int gcol = (colBase + wn * 64 + j * 16 + c15) & 1023;
          const float v = (acc[i][j][r] + bp[gcol]) * scl;
          const int b = grow >> 11, t = grow & 2047;
          const int h = gcol >> 6, d = gcol & 63;
          Ob[((size_t)(b * NHEADS + h) * TSEQ + t) * DK + d] = f2bs(v);
        }
      }
    }
  }
}

// ---------------- output projection: fp32 [M,N] ----------------
__global__ __launch_bounds__(256, 2) void gemm_out_kernel(
    const short* __restrict__ A, const short* __restrict__ BTm,
    const float* __restrict__ bias, float* __restrict__ Cout) {
  GEMM_MAIN_LOOP(A, BTm)
#pragma unroll
  for (int i = 0; i < 4; ++i) {
#pragma unroll
    for (int j = 0; j < 4; ++j) {
#pragma unroll
      for (int r = 0; r < 4; ++r) {
        const int grow = rowBase + wm * 64 + i * 16 + g * 4 + r;
        const int gcol = colBase + wn * 64 + j * 16 + c15;
        Cout[(size_t)grow * 1024 + gcol] = acc[i][j][r] + bias[gcol];
      }
    }
  }
}

// ---------------- flash attention v8b ----------------
// R11 structure (launch_bounds 4 — 5 forced VGPR<=96 and spilled ~1GB to
// scratch in R12) + XCD-aware 1D decode kept: all 16 q-tiles of one bh on one
// XCD so each bh's K/V is served by a single L2 (8 bh x 512KB = 4MB).
__global__ __launch_bounds__(256, 4) void attn_kernel(
    const short* __restrict__ Qg, const short* __restrict__ Kg,
    const short* __restrict__ Vtg, short* __restrict__ ctx) {
  __shared__ short Ks[2][64 * 64];
  __shared__ short VTs[2][64 * 64];

  const int tid = threadIdx.x;
  const int lane = tid & 63;
  const int w = tid >> 6;
  const int l5 = lane >> 5;
  const int c31 = lane & 31;
  // XCD-aware decode of 1D block id (bijective on [0,1024))
  const int lid = blockIdx.x;
  const int bh = (lid >> 7) * 8 + (lid & 7);
  const int qbase = ((lid >> 3) & 15) * 128;
  const int b = bh >> 4, h = bh & 15;

  const short* Qp = Qg + (size_t)bh * TSEQ * DK;
  const short* Kp = Kg + (size_t)bh * TSEQ * DK;
  const short* Vtp = Vtg + (size_t)bh * DK * TSEQ;

  const int qrow = qbase + w * 32 + c31;

  bf16x8 qf[4];
#pragma unroll
  for (int kd = 0; kd < 4; ++kd)
    qf[kd] = *reinterpret_cast<const bf16x8*>(Qp + (size_t)qrow * DK + kd * 16 + l5 * 8);

  f32x16 o0, o1;
#pragma unroll
  for (int r = 0; r < 16; ++r) { o0[r] = 0.f; o1[r] = 0.f; }
  float l_s = 0.f;

  f32x16 z16;
#pragma unroll
  for (int r = 0; r < 16; ++r) z16[r] = 0.f;

  const int srow = w * 8 + (lane >> 3);
  const int soff = ((lane & 7) ^ (lane >> 3) ^ (w & 3)) * 8;
  const int swz = (((c31 & 7) ^ (c31 >> 3)) << 4);

  int offA[4];
#pragma unroll
  for (int kd = 0; kd < 4; ++kd)
    offA[kd] = c31 * 64 + ((((kd * 32 + l5 * 16)) ^ swz) >> 1);

#define STAGE(T, SLOT) do {                                                          \
    const int kt_ = (T) * 64;                                                        \
    _Pragma("unroll")                                                                \
    for (int c = 0; c < 2; ++c) {                                                    \
      const int row_ = c * 32 + srow;                                                \
      gl_lds16(Kp + (size_t)(kt_ + row_) * DK + soff, &Ks[SLOT][(c * 4 + w) * 512]); \
      gl_lds16(Vtp + (size_t)row_ * TSEQ + kt_ + soff, &VTs[SLOT][(c * 4 + w) * 512]); \
    }                                                                                \
  } while (0)

#define BODY(T, SLOT, PREFETCH) do {                                                 \
    asm volatile("s_waitcnt vmcnt(0)" ::: "memory");                                 \
    __builtin_amdgcn_s_barrier();                                                    \
    __builtin_amdgcn_sched_barrier(0);                                               \
    if (PREFETCH) STAGE((T) + 1, (SLOT) ^ 1);                                        \
    const short* ksb = &Ks[SLOT][0];                                                 \
    const short* vtb = &VTs[SLOT][0];                                                \
    __builtin_amdgcn_s_setprio(1);                                                   \
    const bf16x8 kf0a = *reinterpret_cast<const bf16x8*>(ksb + offA[0]);             \
    const bf16x8 kf1a = *reinterpret_cast<const bf16x8*>(ksb + 2048 + offA[0]);      \
    f32x16 s0 = __builtin_amdgcn_mfma_f32_32x32x16_bf16(kf0a, qf[0], z16, 0, 0, 0);  \
    f32x16 s1 = __builtin_amdgcn_mfma_f32_32x32x16_bf16(kf1a, qf[0], z16, 0, 0, 0);  \
    _Pragma("unroll")                                                                \
    for (int kd = 1; kd < 4; ++kd) {                                                 \
      const bf16x8 kf0 = *reinterpret_cast<const bf16x8*>(ksb + offA[kd]);           \
      const bf16x8 kf1 = *reinterpret_cast<const bf16x8*>(ksb + 2048 + offA[kd]);    \
      s0 = __builtin_amdgcn_mfma_f32_32x32x16_bf16(kf0, qf[kd], s0, 0, 0, 0);        \
      s1 = __builtin_amdgcn_mfma_f32_32x32x16_bf16(kf1, qf[kd], s1, 0, 0, 0);        \
    }                                                                                \
    __builtin_amdgcn_s_setprio(0);                                                   \
    float p0 = 0.f, p1 = 0.f, p2 = 0.f, p3 = 0.f;                                    \
    _Pragma("unroll")                                                                \
    for (int r = 0; r < 16; r += 4) {                                                \
      s0[r] = __builtin_amdgcn_exp2f(s0[r]);                                         \
      s0[r + 1] = __builtin_amdgcn_exp2f(s0[r + 1]);                                 \
      s0[r + 2] = __builtin_amdgcn_exp2f(s0[r + 2]);                                 \
      s0[r + 3] = __builtin_amdgcn_exp2f(s0[r + 3]);                                 \
      p0 += s0[r]; p1 += s0[r + 1]; p2 += s0[r + 2]; p3 += s0[r + 3];                \
    }                                                                                \
    _Pragma("unroll")                                                                \
    for (int r = 0; r < 16; r += 4) {                                                \
      s1[r] = __builtin_amdgcn_exp2f(s1[r]);                                         \
      s1[r + 1] = __builtin_amdgcn_exp2f(s1[r + 1]);                                 \
      s1[r + 2] = __builtin_amdgcn_exp2f(s1[r + 2]);                                 \
      s1[r + 3] = __builtin_amdgcn_exp2f(s1[r + 3]);                                 \
      p0 += s1[r]; p1 += s1[r + 1]; p2 += s1[r + 2]; p3 += s1[r + 3];                \
    }                                                                                \
    l_s += (p0 + p1) + (p2 + p3);                                                    \
    uint32_t wa[8], wb[8];                                                           \
    _Pragma("unroll")                                                                \
    for (int t2 = 0; t2 < 8; ++t2) {                                                 \
      wa[t2] = cvt_pk(s0[2 * t2], s0[2 * t2 + 1]);                                   \
      wb[t2] = cvt_pk(s1[2 * t2], s1[2 * t2 + 1]);                                   \
    }                                                                                \
    permswap(wa[0], wa[2]); permswap(wa[1], wa[3]);                                  \
    permswap(wa[4], wa[6]); permswap(wa[5], wa[7]);                                  \
    permswap(wb[0], wb[2]); permswap(wb[1], wb[3]);                                  \
    permswap(wb[4], wb[6]); permswap(wb[5], wb[7]);                                  \
    bf16x8 pf[4];                                                                    \
    {                                                                                \
      union { uint32_t u[4]; bf16x8 v; } fr;                                         \
      fr.u[0] = wa[0]; fr.u[1] = wa[1]; fr.u[2] = wa[2]; fr.u[3] = wa[3]; pf[0] = fr.v; \
      fr.u[0] = wa[4]; fr.u[1] = wa[5]; fr.u[2] = wa[6]; fr.u[3] = wa[7]; pf[1] = fr.v; \
      fr.u[0] = wb[0]; fr.u[1] = wb[1]; fr.u[2] = wb[2]; fr.u[3] = wb[3]; pf[2] = fr.v; \
      fr.u[0] = wb[4]; fr.u[1] = wb[5]; fr.u[2] = wb[6]; fr.u[3] = wb[7]; pf[3] = fr.v; \
    }                                                                                \
    __builtin_amdgcn_s_setprio(1);                                                   \
    _Pragma("unroll")                                                                \
    for (int ks = 0; ks < 4; ++ks) {                                                 \
      const bf16x8 vf0 = *reinterpret_cast<const bf16x8*>(vtb + offA[ks]);           \
      const bf16x8 vf1 = *reinterpret_cast<const bf16x8*>(vtb + 2048 + offA[ks]);    \
      o0 = __builtin_amdgcn_mfma_f32_32x32x16_bf16(vf0, pf[ks], o0, 0, 0, 0);        \
      o1 = __builtin_amdgcn_mfma_f32_32x32x16_bf16(vf1, pf[ks], o1, 0, 0, 0);        \
    }                                                                                \
    __builtin_amdgcn_s_setprio(0);                                                   \
  } while (0)

  STAGE(0, 0);
  for (int t = 0; t < 30; t += 2) {
    BODY(t, 0, true);
    BODY(t + 1, 1, true);
  }
  BODY(30, 0, true);
  BODY(31, 1, false);

#undef STAGE
#undef BODY

  l_s += __shfl_xor(l_s, 32, 64);

  const float inv = 1.0f / l_s;
  short* crow = ctx + ((size_t)b * TSEQ + qrow) * D_MODEL + h * 64;
#pragma unroll
  for (int r = 0; r < 16; ++r) {
    const int d = (r & 3) + 8 * (r >> 2) + 4 * l5;
    crow[d] = f2bs(o0[r] * inv);
    crow[32 + d] = f2bs(o1[r] * inv);
  }
}

extern "C" void kernel_launch(void* const* d_in, const int* in_sizes, int n_in,
                              void* d_out, int out_size, void* d_ws, size_t ws_size,
                              hipStream_t stream) {
  const float* x  = (const float*)d_in[0];
  const float* Wq = (const float*)d_in[1];
  const float* bq = (const float*)d_in[2];
  const float* Wk = (const float*)d_in[3];
  const float* bk = (const float*)d_in[4];
  const float* Wv = (const float*)d_in[5];
  const float* bv = (const float*)d_in[6];
  const float* Wo = (const float*)d_in[7];
  const float* bo = (const float*)d_in[8];
  float* out = (float*)d_out;

  short* xb   = (short*)d_ws;                       // 8192*1024 bf16 (reused as ctx)
  short* WqT  = xb + (size_t)MROWS * D_MODEL;       // WqT/WkT/WvT contiguous: fused B
  short* WkT  = WqT + (size_t)D_MODEL * D_MODEL;
  short* WvT  = WkT + (size_t)D_MODEL * D_MODEL;
  short* WoT  = WvT + (size_t)D_MODEL * D_MODEL;
  short* Qb   = WoT + (size_t)D_MODEL * D_MODEL;
  short* Kb   = Qb + (size_t)MROWS * D_MODEL;
  short* Vtb  = Kb + (size_t)MROWS * D_MODEL;       // V^T layout [B,H,dk,T]
  short* ctxb = xb;                                 // xb dead after QKV projection

  const float CL = 0.1803368801111204f;             // 0.125 * log2(e), folded into Q

  cast_x_kernel<<<(MROWS * D_MODEL / 4 + 255) / 256, 256, 0, stream>>>(x, xb, MROWS * D_MODEL / 4);
  dim3 tb(32, 8), tg(32, 32);
  transpose_cast_kernel<<<tg, tb, 0, stream>>>(Wq, WqT);
  transpose_cast_kernel<<<tg, tb, 0, stream>>>(Wk, WkT);
  transpose_cast_kernel<<<tg, tb, 0, stream>>>(Wv, WvT);
  transpose_cast_kernel<<<tg, tb, 0, stream>>>(Wo, WoT);

  gemm_qkv_kernel<<<dim3(MROWS / 128, 3 * D_MODEL / 128), 256, 0, stream>>>(
      xb, WqT, bq, bk, bv, Qb, Kb, Vtb, CL);

  attn_kernel<<<1024, 256, 0, stream>>>(Qb, Kb, Vtb, ctxb);

  gemm_out_kernel<<<dim3(MROWS / 128, D_MODEL / 128), 256, 0, stream>>>(ctxb, WoT, bo, out);
}

// Round 15
// 167.360 us; speedup vs baseline: 2.7559x; 1.1129x over previous
//
#include <hip/hip_runtime.h>
#include <hip/hip_bf16.h>
#include <stdint.h>

#define D_MODEL 1024
#define NHEADS  16
#define DK      64
#define TSEQ    2048
#define BATCH   4
#define MROWS   8192   // B*T

typedef __attribute__((ext_vector_type(8))) short bf16x8;
typedef __attribute__((ext_vector_type(4))) float f32x4;
typedef __attribute__((ext_vector_type(16))) float f32x16;

__device__ __forceinline__ void gl_lds16(const void* g, void* l) {
  __builtin_amdgcn_global_load_lds(
      (const __attribute__((address_space(1))) unsigned int*)g,
      (__attribute__((address_space(3))) unsigned int*)l,
      16, 0, 0);
}

__device__ __forceinline__ short f2bs(float f) {
  union { __hip_bfloat16 h; short s; } u;
  u.h = __float2bfloat16(f);
  return u.s;
}

// packed f32->bf16 pair conversion. s_nop 1 guards the TRANS(v_exp)->read
// hazard (hazard recognizer does not insert waits for INLINEASM consumers).
__device__ __forceinline__ uint32_t cvt_pk(float lo, float hi) {
  uint32_t r;
  asm("s_nop 1\n\tv_cvt_pk_bf16_f32 %0, %1, %2" : "=v"(r) : "v"(lo), "v"(hi));
  return r;
}

// v_permlane32_swap_b32: a' = {a_lo, b_lo}, b' = {a_hi, b_hi}
__device__ __forceinline__ void permswap(uint32_t& a, uint32_t& b) {
  asm("v_permlane32_swap_b32 %0, %1" : "+v"(a), "+v"(b));
}

// ---------------- cast x (fp32 -> bf16), vectorized ----------------
__global__ void cast_x_kernel(const float* __restrict__ in, short* __restrict__ out, int n4) {
  int i = blockIdx.x * blockDim.x + threadIdx.x;
  if (i >= n4) return;
  const float4 v = reinterpret_cast<const float4*>(in)[i];
  short4 r;
  r.x = f2bs(v.x); r.y = f2bs(v.y); r.z = f2bs(v.z); r.w = f2bs(v.w);
  reinterpret_cast<short4*>(out)[i] = r;
}

// ---------- transpose + cast all 4 weights in one launch (z selects) ----------
__global__ void transpose_cast4_kernel(
    const float* __restrict__ s0, const float* __restrict__ s1,
    const float* __restrict__ s2, const float* __restrict__ s3,
    short* __restrict__ d0, short* __restrict__ d1,
    short* __restrict__ d2, short* __restrict__ d3) {
  const int z = blockIdx.z;
  const float* src = (z == 0) ? s0 : (z == 1) ? s1 : (z == 2) ? s2 : s3;
  short* dst = (z == 0) ? d0 : (z == 1) ? d1 : (z == 2) ? d2 : d3;
  __shared__ float tile[32][33];
  const int tx = threadIdx.x, ty = threadIdx.y;
  const int n0 = blockIdx.x * 32, k0 = blockIdx.y * 32;
#pragma unroll
  for (int r = 0; r < 32; r += 8)
    tile[ty + r][tx] = src[(size_t)(k0 + ty + r) * D_MODEL + n0 + tx];
  __syncthreads();
#pragma unroll
  for (int r = 0; r < 32; r += 8)
    dst[(size_t)(n0 + ty + r) * D_MODEL + k0 + tx] = f2bs(tile[tx][ty + r]);
}

// ---------------- GEMM main-loop: 2-phase stage-ahead, BK=64, 128B LDS rows ----
// One gl_lds16 covers 8 rows of 128B -> 4 calls/wave/operand (R14 bug: only 2,
// half the tile unstaged -> NaN). LDS[row][chunk] = G[row][chunk ^ (row&7)],
// chunk = 16B unit. Fragment read chunk = (kk*4+g) ^ (c15&7): conflict-free
// (attn-proven, R10->R11 A/B: 8.4M->0). 16 K-iters; 64KB LDS -> 2 blocks/CU.
#define GEMM_MAIN_LOOP(A_, BT_)                                                     \
  __shared__ short SM[2][16384];  /* [buf][A 0..8191 | B 8192..16383] */            \
  const int tid = threadIdx.x;                                                      \
  const int lane = tid & 63;                                                        \
  const int w = tid >> 6;                                                           \
  const int wm = w >> 1, wn = w & 1;                                                \
  const int rowBase = blockIdx.x * 128;                                             \
  const int colBase = blockIdx.y * 128;                                             \
  const int g = lane >> 4;                                                          \
  const int c15 = lane & 15;                                                        \
  f32x4 acc[4][4];                                                                  \
  _Pragma("unroll")                                                                 \
  for (int i = 0; i < 4; ++i)                                                       \
    _Pragma("unroll")                                                               \
    for (int j = 0; j < 4; ++j) acc[i][j] = {0.f, 0.f, 0.f, 0.f};                   \
  const int srow = lane >> 3;                                                       \
  const int schunk8 = ((lane & 7) ^ srow) * 8;                                      \
  const short* gA = (A_) + (size_t)(rowBase + w * 32 + srow) * 1024 + schunk8;      \
  const short* gB = (BT_) + (size_t)(colBase + w * 32 + srow) * 1024 + schunk8;     \
  const int ko0 = ((g) ^ (c15 & 7)) * 8;                                            \
  const int ko1 = ((4 + g) ^ (c15 & 7)) * 8;                                        \
  _Pragma("unroll")                                                                 \
  for (int c = 0; c < 4; ++c) {                                                     \
    gl_lds16(gA + (size_t)(c * 8) * 1024, &SM[0][(w * 32 + c * 8) * 64]);           \
    gl_lds16(gB + (size_t)(c * 8) * 1024, &SM[0][8192 + (w * 32 + c * 8) * 64]);    \
  }                                                                                 \
  _Pragma("unroll 2")                                                               \
  for (int kt = 0; kt < 1024; kt += 64) {                                           \
    const int buf = (kt >> 6) & 1;                                                  \
    asm volatile("s_waitcnt vmcnt(0)" ::: "memory");                                \
    __builtin_amdgcn_s_barrier();                                                   \
    __builtin_amdgcn_sched_barrier(0);                                              \
    if (kt + 64 < 1024) {                                                           \
      _Pragma("unroll")                                                             \
      for (int c = 0; c < 4; ++c) {                                                 \
        gl_lds16(gA + (size_t)(c * 8) * 1024 + kt + 64, &SM[buf ^ 1][(w * 32 + c * 8) * 64]); \
        gl_lds16(gB + (size_t)(c * 8) * 1024 + kt + 64, &SM[buf ^ 1][8192 + (w * 32 + c * 8) * 64]); \
      }                                                                             \
    }                                                                               \
    const short* smA = &SM[buf][0];                                                 \
    const short* smB = &SM[buf][8192];                                              \
    bf16x8 af[4][2], bfr[4][2];                                                     \
    _Pragma("unroll")                                                               \
    for (int i = 0; i < 4; ++i) {                                                   \
      const int rb = (wm * 64 + i * 16 + c15) * 64;                                 \
      af[i][0] = *reinterpret_cast<const bf16x8*>(&smA[rb + ko0]);                  \
      af[i][1] = *reinterpret_cast<const bf16x8*>(&smA[rb + ko1]);                  \
    }                                                                               \
    _Pragma("unroll")                                                               \
    for (int j = 0; j < 4; ++j) {                                                   \
      const int rb = (wn * 64 + j * 16 + c15) * 64;                                 \
      bfr[j][0] = *reinterpret_cast<const bf16x8*>(&smB[rb + ko0]);                 \
      bfr[j][1] = *reinterpret_cast<const bf16x8*>(&smB[rb + ko1]);                 \
    }                                                                               \
    __builtin_amdgcn_s_setprio(1);                                                  \
    _Pragma("unroll")                                                               \
    for (int kk = 0; kk < 2; ++kk)                                                  \
      _Pragma("unroll")                                                             \
      for (int i = 0; i < 4; ++i)                                                   \
        _Pragma("unroll")                                                           \
        for (int j = 0; j < 4; ++j)                                                 \
          acc[i][j] = __builtin_amdgcn_mfma_f32_16x16x32_bf16(af[i][kk], bfr[j][kk], acc[i][j], 0, 0, 0); \
    __builtin_amdgcn_s_setprio(0);                                                  \
  }                                                                                 \
  __syncthreads();

// ---------------- fused QKV projection: C[8192,3072], scatter per sub-matrix ----
__global__ __launch_bounds__(256, 2) void gemm_qkv_kernel(
    const short* __restrict__ A, const short* __restrict__ BTm,
    const float* __restrict__ bq, const float* __restrict__ bk,
    const float* __restrict__ bv, short* __restrict__ Qb,
    short* __restrict__ Kb, short* __restrict__ Vtb, float CL) {
  GEMM_MAIN_LOOP(A, BTm)
  const int mat = colBase >> 10;                       // uniform per block
  if (mat == 2) {
    // scatter acc -> LDS [d][t ^ ((d&15)<<3)] (pairs packed via cvt_pk)
    short* smf = &SM[0][0];                            // 16384 shorts = 128x128
    const int d_base = wn * 64 + c15;
#pragma unroll
    for (int j = 0; j < 4; ++j) {
      const int dl = d_base + j * 16;
      const int gcol = (colBase & 1023) + dl;
      const float bb = bv[gcol];
      const int sw = (dl & 15) << 3;
#pragma unroll
      for (int i = 0; i < 4; ++i) {
        const int tb = wm * 64 + i * 16 + g * 4;
#pragma unroll
        for (int r = 0; r < 4; r += 2) {
          const uint32_t p = cvt_pk(acc[i][j][r] + bb, acc[i][j][r + 1] + bb);
          *reinterpret_cast<uint32_t*>(&smf[dl * 128 + ((tb + r) ^ sw)]) = p;
        }
      }
    }
    __syncthreads();
    const int b0 = rowBase >> 11, t0 = rowBase & 2047;
    const int vcolBase = colBase & 1023;
#pragma unroll
    for (int k = 0; k < 8; ++k) {
      const int cid = k * 256 + tid;                   // 2048 chunks of 8 shorts
      const int d = cid >> 4;
      const int c = cid & 15;
      const bf16x8 vv = *reinterpret_cast<const bf16x8*>(
          &smf[d * 128 + ((c * 8) ^ ((d & 15) << 3))]);
      *reinterpret_cast<bf16x8*>(
          &Vtb[((size_t)(b0 * 1024 + vcolBase + d)) * 2048 + t0 + c * 8]) = vv;
    }
  } else {
    const float* bp = (mat == 0) ? bq : bk;
    const float scl = (mat == 0) ? CL : 1.0f;
    short* Ob = (mat == 0) ? Qb : Kb;
#pragma unroll
    for (int i = 0; i < 4; ++i) {
#pragma unroll
      for (int j = 0; j < 4; ++j) {
#pragma unroll
        for (int r = 0; r < 4; ++r) {
          const int grow = rowBase + wm * 64 + i * 16 + g * 4 + r;
          const int gcol = (colBase + wn * 64 + j * 16 + c15) & 1023;
          const float v = (acc[i][j][r] + bp[gcol]) * scl;
          const int b = grow >> 11, t = grow & 2047;
          const int h = gcol >> 6, d = gcol & 63;
          Ob[((size_t)(b * NHEADS + h) * TSEQ + t) * DK + d] = f2bs(v);
        }
      }
    }
  }
}

// ---------------- output projection: fp32 [M,N] ----------------
__global__ __launch_bounds__(256, 2) void gemm_out_kernel(
    const short* __restrict__ A, const short* __restrict__ BTm,
    const float* __restrict__ bias, float* __restrict__ Cout) {
  GEMM_MAIN_LOOP(A, BTm)
#pragma unroll
  for (int i = 0; i < 4; ++i) {
#pragma unroll
    for (int j = 0; j < 4; ++j) {
#pragma unroll
      for (int r = 0; r < 4; ++r) {
        const int grow = rowBase + wm * 64 + i * 16 + g * 4 + r;
        const int gcol = colBase + wn * 64 + j * 16 + c15;
        Cout[(size_t)grow * 1024 + gcol] = acc[i][j][r] + bias[gcol];
      }
    }
  }
}

// ---------------- flash attention v8b (unchanged from R13) ----------------
__global__ __launch_bounds__(256, 4) void attn_kernel(
    const short* __restrict__ Qg, const short* __restrict__ Kg,
    const short* __restrict__ Vtg, short* __restrict__ ctx) {
  __shared__ short Ks[2][64 * 64];
  __shared__ short VTs[2][64 * 64];

  const int tid = threadIdx.x;
  const int lane = tid & 63;
  const int w = tid >> 6;
  const int l5 = lane >> 5;
  const int c31 = lane & 31;
  // XCD-aware decode of 1D block id (bijective on [0,1024))
  const int lid = blockIdx.x;
  const int bh = (lid >> 7) * 8 + (lid & 7);
  const int qbase = ((lid >> 3) & 15) * 128;
  const int b = bh >> 4, h = bh & 15;

  const short* Qp = Qg + (size_t)bh * TSEQ * DK;
  const short* Kp = Kg + (size_t)bh * TSEQ * DK;
  const short* Vtp = Vtg + (size_t)bh * DK * TSEQ;

  const int qrow = qbase + w * 32 + c31;

  bf16x8 qf[4];
#pragma unroll
  for (int kd = 0; kd < 4; ++kd)
    qf[kd] = *reinterpret_cast<const bf16x8*>(Qp + (size_t)qrow * DK + kd * 16 + l5 * 8);

  f32x16 o0, o1;
#pragma unroll
  for (int r = 0; r < 16; ++r) { o0[r] = 0.f; o1[r] = 0.f; }
  float l_s = 0.f;

  f32x16 z16;
#pragma unroll
  for (int r = 0; r < 16; ++r) z16[r] = 0.f;

  const int srow = w * 8 + (lane >> 3);
  const int soff = ((lane & 7) ^ (lane >> 3) ^ (w & 3)) * 8;
  const int swz = (((c31 & 7) ^ (c31 >> 3)) << 4);

  int offA[4];
#pragma unroll
  for (int kd = 0; kd < 4; ++kd)
    offA[kd] = c31 * 64 + ((((kd * 32 + l5 * 16)) ^ swz) >> 1);

#define STAGE(T, SLOT) do {                                                          \
    const int kt_ = (T) * 64;                                                        \
    _Pragma("unroll")                                                                \
    for (int c = 0; c < 2; ++c) {                                                    \
      const int row_ = c * 32 + srow;                                                \
      gl_lds16(Kp + (size_t)(kt_ + row_) * DK + soff, &Ks[SLOT][(c * 4 + w) * 512]); \
      gl_lds16(Vtp + (size_t)row_ * TSEQ + kt_ + soff, &VTs[SLOT][(c * 4 + w) * 512]); \
    }                                                                                \
  } while (0)

#define BODY(T, SLOT, PREFETCH) do {                                                 \
    asm volatile("s_waitcnt vmcnt(0)" ::: "memory");                                 \
    __builtin_amdgcn_s_barrier();                                                    \
    __builtin_amdgcn_sched_barrier(0);                                               \
    if (PREFETCH) STAGE((T) + 1, (SLOT) ^ 1);                                        \
    const short* ksb = &Ks[SLOT][0];                                                 \
    const short* vtb = &VTs[SLOT][0];                                                \
    __builtin_amdgcn_s_setprio(1);                                                   \
    const bf16x8 kf0a = *reinterpret_cast<const bf16x8*>(ksb + offA[0]);             \
    const bf16x8 kf1a = *reinterpret_cast<const bf16x8*>(ksb + 2048 + offA[0]);      \
    f32x16 s0 = __builtin_amdgcn_mfma_f32_32x32x16_bf16(kf0a, qf[0], z16, 0, 0, 0);  \
    f32x16 s1 = __builtin_amdgcn_mfma_f32_32x32x16_bf16(kf1a, qf[0], z16, 0, 0, 0);  \
    _Pragma("unroll")                                                                \
    for (int kd = 1; kd < 4; ++kd) {                                                 \
      const bf16x8 kf0 = *reinterpret_cast<const bf16x8*>(ksb + offA[kd]);           \
      const bf16x8 kf1 = *reinterpret_cast<const bf16x8*>(ksb + 2048 + offA[kd]);    \
      s0 = __builtin_amdgcn_mfma_f32_32x32x16_bf16(kf0, qf[kd], s0, 0, 0, 0);        \
      s1 = __builtin_amdgcn_mfma_f32_32x32x16_bf16(kf1, qf[kd], s1, 0, 0, 0);        \
    }                                                                                \
    __builtin_amdgcn_s_setprio(0);                                                   \
    float p0 = 0.f, p1 = 0.f, p2 = 0.f, p3 = 0.f;                                    \
    _Pragma("unroll")                                                                \
    for (int r = 0; r < 16; r += 4) {                                                \
      s0[r] = __builtin_amdgcn_exp2f(s0[r]);                                         \
      s0[r + 1] = __builtin_amdgcn_exp2f(s0[r + 1]);                                 \
      s0[r + 2] = __builtin_amdgcn_exp2f(s0[r + 2]);                                 \
      s0[r + 3] = __builtin_amdgcn_exp2f(s0[r + 3]);                                 \
      p0 += s0[r]; p1 += s0[r + 1]; p2 += s0[r + 2]; p3 += s0[r + 3];                \
    }                                                                                \
    _Pragma("unroll")                                                                \
    for (int r = 0; r < 16; r += 4) {                                                \
      s1[r] = __builtin_amdgcn_exp2f(s1[r]);                                         \
      s1[r + 1] = __builtin_amdgcn_exp2f(s1[r + 1]);                                 \
      s1[r + 2] = __builtin_amdgcn_exp2f(s1[r + 2]);                                 \
      s1[r + 3] = __builtin_amdgcn_exp2f(s1[r + 3]);                                 \
      p0 += s1[r]; p1 += s1[r + 1]; p2 += s1[r + 2]; p3 += s1[r + 3];                \
    }                                                                                \
    l_s += (p0 + p1) + (p2 + p3);                                                    \
    uint32_t wa[8], wb[8];                                                           \
    _Pragma("unroll")                                                                \
    for (int t2 = 0; t2 < 8; ++t2) {                                                 \
      wa[t2] = cvt_pk(s0[2 * t2], s0[2 * t2 + 1]);                                   \
      wb[t2] = cvt_pk(s1[2 * t2], s1[2 * t2 + 1]);                                   \
    }                                                                                \
    permswap(wa[0], wa[2]); permswap(wa[1], wa[3]);                                  \
    permswap(wa[4], wa[6]); permswap(wa[5], wa[7]);                                  \
    permswap(wb[0], wb[2]); permswap(wb[1], wb[3]);                                  \
    permswap(wb[4], wb[6]); permswap(wb[5], wb[7]);                                  \
    bf16x8 pf[4];                                                                    \
    {                                                                                \
      union { uint32_t u[4]; bf16x8 v; } fr;                                         \
      fr.u[0] = wa[0]; fr.u[1] = wa[1]; fr.u[2] = wa[2]; fr.u[3] = wa[3]; pf[0] = fr.v; \
      fr.u[0] = wa[4]; fr.u[1] = wa[5]; fr.u[2] = wa[6]; fr.u[3] = wa[7]; pf[1] = fr.v; \
      fr.u[0] = wb[0]; fr.u[1] = wb[1]; fr.u[2] = wb[2]; fr.u[3] = wb[3]; pf[2] = fr.v; \
      fr.u[0] = wb[4]; fr.u[1] = wb[5]; fr.u[2] = wb[6]; fr.u[3] = wb[7]; pf[3] = fr.v; \
    }                                                                                \
    __builtin_amdgcn_s_setprio(1);                                                   \
    _Pragma("unroll")                                                                \
    for (int ks = 0; ks < 4; ++ks) {                                                 \
      const bf16x8 vf0 = *reinterpret_cast<const bf16x8*>(vtb + offA[ks]);           \
      const bf16x8 vf1 = *reinterpret_cast<const bf16x8*>(vtb + 2048 + offA[ks]);    \
      o0 = __builtin_amdgcn_mfma_f32_32x32x16_bf16(vf0, pf[ks], o0, 0, 0, 0);        \
      o1 = __builtin_amdgcn_mfma_f32_32x32x16_bf16(vf1, pf[ks], o1, 0, 0, 0);        \
    }                                                                                \
    __builtin_amdgcn_s_setprio(0);                                                   \
  } while (0)

  STAGE(0, 0);
  for (int t = 0; t < 30; t += 2) {
    BODY(t, 0, true);
    BODY(t + 1, 1, true);
  }
  BODY(30, 0, true);
  BODY(31, 1, false);

#undef STAGE
#undef BODY

  l_s += __shfl_xor(l_s, 32, 64);

  const float inv = 1.0f / l_s;
  short* crow = ctx + ((size_t)b * TSEQ + qrow) * D_MODEL + h * 64;
#pragma unroll
  for (int r = 0; r < 16; ++r) {
    const int d = (r & 3) + 8 * (r >> 2) + 4 * l5;
    crow[d] = f2bs(o0[r] * inv);
    crow[32 + d] = f2bs(o1[r] * inv);
  }
}

extern "C" void kernel_launch(void* const* d_in, const int* in_sizes, int n_in,
                              void* d_out, int out_size, void* d_ws, size_t ws_size,
                              hipStream_t stream) {
  const float* x  = (const float*)d_in[0];
  const float* Wq = (const float*)d_in[1];
  const float* bq = (const float*)d_in[2];
  const float* Wk = (const float*)d_in[3];
  const float* bk = (const float*)d_in[4];
  const float* Wv = (const float*)d_in[5];
  const float* bv = (const float*)d_in[6];
  const float* Wo = (const float*)d_in[7];
  const float* bo = (const float*)d_in[8];
  float* out = (float*)d_out;

  short* xb   = (short*)d_ws;                       // 8192*1024 bf16 (reused as ctx)
  short* WqT  = xb + (size_t)MROWS * D_MODEL;       // WqT/WkT/WvT contiguous: fused B
  short* WkT  = WqT + (size_t)D_MODEL * D_MODEL;
  short* WvT  = WkT + (size_t)D_MODEL * D_MODEL;
  short* WoT  = WvT + (size_t)D_MODEL * D_MODEL;
  short* Qb   = WoT + (size_t)D_MODEL * D_MODEL;
  short* Kb   = Qb + (size_t)MROWS * D_MODEL;
  short* Vtb  = Kb + (size_t)MROWS * D_MODEL;       // V^T layout [B,H,dk,T]
  short* ctxb = xb;                                 // xb dead after QKV projection

  const float CL = 0.1803368801111204f;             // 0.125 * log2(e), folded into Q

  cast_x_kernel<<<(MROWS * D_MODEL / 4 + 255) / 256, 256, 0, stream>>>(x, xb, MROWS * D_MODEL / 4);
  transpose_cast4_kernel<<<dim3(32, 32, 4), dim3(32, 8), 0, stream>>>(
      Wq, Wk, Wv, Wo, WqT, WkT, WvT, WoT);

  gemm_qkv_kernel<<<dim3(MROWS / 128, 3 * D_MODEL / 128), 256, 0, stream>>>(
      xb, WqT, bq, bk, bv, Qb, Kb, Vtb, CL);

  attn_kernel<<<1024, 256, 0, stream>>>(Qb, Kb, Vtb, ctxb);

  gemm_out_kernel<<<dim3(MROWS / 128, D_MODEL / 128), 256, 0, stream>>>(ctxb, WoT, bo, out);
}

// Round 16
// 164.202 us; speedup vs baseline: 2.8089x; 1.0192x over previous
//
#include <hip/hip_runtime.h>
#include <hip/hip_bf16.h>
#include <stdint.h>

#define D_MODEL 1024
#define NHEADS  16
#define DK      64
#define TSEQ    2048
#define BATCH   4
#define MROWS   8192   // B*T

typedef __attribute__((ext_vector_type(8))) short bf16x8;
typedef __attribute__((ext_vector_type(4))) float f32x4;
typedef __attribute__((ext_vector_type(16))) float f32x16;

__device__ __forceinline__ void gl_lds16(const void* g, void* l) {
  __builtin_amdgcn_global_load_lds(
      (const __attribute__((address_space(1))) unsigned int*)g,
      (__attribute__((address_space(3))) unsigned int*)l,
      16, 0, 0);
}

__device__ __forceinline__ short f2bs(float f) {
  union { __hip_bfloat16 h; short s; } u;
  u.h = __float2bfloat16(f);
  return u.s;
}

// packed f32->bf16 pair conversion. s_nop 1 guards the TRANS(v_exp)->read
// hazard (hazard recognizer does not insert waits for INLINEASM consumers).
__device__ __forceinline__ uint32_t cvt_pk(float lo, float hi) {
  uint32_t r;
  asm("s_nop 1\n\tv_cvt_pk_bf16_f32 %0, %1, %2" : "=v"(r) : "v"(lo), "v"(hi));
  return r;
}

// v_permlane32_swap_b32: a' = {a_lo, b_lo}, b' = {a_hi, b_hi}
__device__ __forceinline__ void permswap(uint32_t& a, uint32_t& b) {
  asm("v_permlane32_swap_b32 %0, %1" : "+v"(a), "+v"(b));
}

// ---------- fused prep: 4 weight transposes (z<4) + x cast (z>=4) ----------
// grid (32,32,8), block (32,8).
__global__ void prep_kernel(
    const float* __restrict__ x, short* __restrict__ xb,
    const float* __restrict__ s0, const float* __restrict__ s1,
    const float* __restrict__ s2, const float* __restrict__ s3,
    short* __restrict__ d0, short* __restrict__ d1,
    short* __restrict__ d2, short* __restrict__ d3) {
  const int z = blockIdx.z;
  if (z < 4) {
    const float* src = (z == 0) ? s0 : (z == 1) ? s1 : (z == 2) ? s2 : s3;
    short* dst = (z == 0) ? d0 : (z == 1) ? d1 : (z == 2) ? d2 : d3;
    __shared__ float tile[32][33];
    const int tx = threadIdx.x, ty = threadIdx.y;
    const int n0 = blockIdx.x * 32, k0 = blockIdx.y * 32;
#pragma unroll
    for (int r = 0; r < 32; r += 8)
      tile[ty + r][tx] = src[(size_t)(k0 + ty + r) * D_MODEL + n0 + tx];
    __syncthreads();
#pragma unroll
    for (int r = 0; r < 32; r += 8)
      dst[(size_t)(n0 + ty + r) * D_MODEL + k0 + tx] = f2bs(tile[tx][ty + r]);
  } else {
    // cast 8192x1024 f32 -> bf16, 2 float4 per thread
    const int c = (z - 4) * 1024 + blockIdx.y * 32 + blockIdx.x;   // [0,4096)
    const int base = (c * 256 + (int)(threadIdx.y * 32 + threadIdx.x)) * 2;
#pragma unroll
    for (int q = 0; q < 2; ++q) {
      const int i = base + q;
      const float4 v = reinterpret_cast<const float4*>(x)[i];
      short4 r;
      r.x = f2bs(v.x); r.y = f2bs(v.y); r.z = f2bs(v.z); r.w = f2bs(v.w);
      reinterpret_cast<short4*>(xb)[i] = r;
    }
  }
}

// ---------------- GEMM main-loop: 2-phase stage-ahead, BK=64, 128B LDS rows ----
// One gl_lds16 covers 8 rows of 128B -> 4 calls/wave/operand. LDS[row][chunk] =
// G[row][chunk ^ (row&7)], chunk = 16B unit. Fragment read chunk =
// (kk*4+g) ^ (c15&7): conflict-free. 16 K-iters; 64KB LDS -> 2 blocks/CU.
#define GEMM_MAIN_LOOP(A_, BT_)                                                     \
  __shared__ short SM[2][16384];  /* [buf][A 0..8191 | B 8192..16383] */            \
  const int tid = threadIdx.x;                                                      \
  const int lane = tid & 63;                                                        \
  const int w = tid >> 6;                                                           \
  const int wm = w >> 1, wn = w & 1;                                                \
  const int rowBase = blockIdx.x * 128;                                             \
  const int colBase = blockIdx.y * 128;                                             \
  const int g = lane >> 4;                                                          \
  const int c15 = lane & 15;                                                        \
  f32x4 acc[4][4];                                                                  \
  _Pragma("unroll")                                                                 \
  for (int i = 0; i < 4; ++i)                                                       \
    _Pragma("unroll")                                                               \
    for (int j = 0; j < 4; ++j) acc[i][j] = {0.f, 0.f, 0.f, 0.f};                   \
  const int srow = lane >> 3;                                                       \
  const int schunk8 = ((lane & 7) ^ srow) * 8;                                      \
  const short* gA = (A_) + (size_t)(rowBase + w * 32 + srow) * 1024 + schunk8;      \
  const short* gB = (BT_) + (size_t)(colBase + w * 32 + srow) * 1024 + schunk8;     \
  const int ko0 = ((g) ^ (c15 & 7)) * 8;                                            \
  const int ko1 = ((4 + g) ^ (c15 & 7)) * 8;                                        \
  _Pragma("unroll")                                                                 \
  for (int c = 0; c < 4; ++c) {                                                     \
    gl_lds16(gA + (size_t)(c * 8) * 1024, &SM[0][(w * 32 + c * 8) * 64]);           \
    gl_lds16(gB + (size_t)(c * 8) * 1024, &SM[0][8192 + (w * 32 + c * 8) * 64]);    \
  }                                                                                 \
  _Pragma("unroll 2")                                                               \
  for (int kt = 0; kt < 1024; kt += 64) {                                           \
    const int buf = (kt >> 6) & 1;                                                  \
    asm volatile("s_waitcnt vmcnt(0)" ::: "memory");                                \
    __builtin_amdgcn_s_barrier();                                                   \
    __builtin_amdgcn_sched_barrier(0);                                              \
    if (kt + 64 < 1024) {                                                           \
      _Pragma("unroll")                                                             \
      for (int c = 0; c < 4; ++c) {                                                 \
        gl_lds16(gA + (size_t)(c * 8) * 1024 + kt + 64, &SM[buf ^ 1][(w * 32 + c * 8) * 64]); \
        gl_lds16(gB + (size_t)(c * 8) * 1024 + kt + 64, &SM[buf ^ 1][8192 + (w * 32 + c * 8) * 64]); \
      }                                                                             \
    }                                                                               \
    const short* smA = &SM[buf][0];                                                 \
    const short* smB = &SM[buf][8192];                                              \
    bf16x8 af[4][2], bfr[4][2];                                                     \
    _Pragma("unroll")                                                               \
    for (int i = 0; i < 4; ++i) {                                                   \
      const int rb = (wm * 64 + i * 16 + c15) * 64;                                 \
      af[i][0] = *reinterpret_cast<const bf16x8*>(&smA[rb + ko0]);                  \
      af[i][1] = *reinterpret_cast<const bf16x8*>(&smA[rb + ko1]);                  \
    }                                                                               \
    _Pragma("unroll")                                                               \
    for (int j = 0; j < 4; ++j) {                                                   \
      const int rb = (wn * 64 + j * 16 + c15) * 64;                                 \
      bfr[j][0] = *reinterpret_cast<const bf16x8*>(&smB[rb + ko0]);                 \
      bfr[j][1] = *reinterpret_cast<const bf16x8*>(&smB[rb + ko1]);                 \
    }                                                                               \
    __builtin_amdgcn_s_setprio(1);                                                  \
    _Pragma("unroll")                                                               \
    for (int kk = 0; kk < 2; ++kk)                                                  \
      _Pragma("unroll")                                                             \
      for (int i = 0; i < 4; ++i)                                                   \
        _Pragma("unroll")                                                           \
        for (int j = 0; j < 4; ++j)                                                 \
          acc[i][j] = __builtin_amdgcn_mfma_f32_16x16x32_bf16(af[i][kk], bfr[j][kk], acc[i][j], 0, 0, 0); \
    __builtin_amdgcn_s_setprio(0);                                                  \
  }                                                                                 \
  __syncthreads();

// ---------------- fused QKV projection: C[8192,3072], scatter per sub-matrix ----
__global__ __launch_bounds__(256, 2) void gemm_qkv_kernel(
    const short* __restrict__ A, const short* __restrict__ BTm,
    const float* __restrict__ bq, const float* __restrict__ bk,
    const float* __restrict__ bv, short* __restrict__ Qb,
    short* __restrict__ Kb, short* __restrict__ Vtb, float CL) {
  GEMM_MAIN_LOOP(A, BTm)
  const int mat = colBase >> 10;                       // uniform per block
  if (mat == 2) {
    // scatter acc -> LDS [d][t ^ ((d&15)<<3)] (pairs packed via cvt_pk)
    short* smf = &SM[0][0];                            // 16384 shorts = 128x128
    const int d_base = wn * 64 + c15;
#pragma unroll
    for (int j = 0; j < 4; ++j) {
      const int dl = d_base + j * 16;
      const int gcol = (colBase & 1023) + dl;
      const float bb = bv[gcol];
      const int sw = (dl & 15) << 3;
#pragma unroll
      for (int i = 0; i < 4; ++i) {
        const int tb = wm * 64 + i * 16 + g * 4;
#pragma unroll
        for (int r = 0; r < 4; r += 2) {
          const uint32_t p = cvt_pk(acc[i][j][r] + bb, acc[i][j][r + 1] + bb);
          *reinterpret_cast<uint32_t*>(&smf[dl * 128 + ((tb + r) ^ sw)]) = p;
        }
      }
    }
    __syncthreads();
    const int b0 = rowBase >> 11, t0 = rowBase & 2047;
    const int vcolBase = colBase & 1023;
#pragma unroll
    for (int k = 0; k < 8; ++k) {
      const int cid = k * 256 + tid;                   // 2048 chunks of 8 shorts
      const int d = cid >> 4;
      const int c = cid & 15;
      const bf16x8 vv = *reinterpret_cast<const bf16x8*>(
          &smf[d * 128 + ((c * 8) ^ ((d & 15) << 3))]);
      *reinterpret_cast<bf16x8*>(
          &Vtb[((size_t)(b0 * 1024 + vcolBase + d)) * 2048 + t0 + c * 8]) = vv;
    }
  } else {
    const float* bp = (mat == 0) ? bq : bk;
    const float scl = (mat == 0) ? CL : 1.0f;
    short* Ob = (mat == 0) ? Qb : Kb;
#pragma unroll
    for (int i = 0; i < 4; ++i) {
#pragma unroll
      for (int j = 0; j < 4; ++j) {
#pragma unroll
        for (int r = 0; r < 4; ++r) {
          const int grow = rowBase + wm * 64 + i * 16 + g * 4 + r;
          const int gcol = (colBase + wn * 64 + j * 16 + c15) & 1023;
          const float v = (acc[i][j][r] + bp[gcol]) * scl;
          const int b = grow >> 11, t = grow & 2047;
          const int h = gcol >> 6, d = gcol & 63;
          Ob[((size_t)(b * NHEADS + h) * TSEQ + t) * DK + d] = f2bs(v);
        }
      }
    }
  }
}

// ---------------- output projection: fp32 [M,N] ----------------
__global__ __launch_bounds__(256, 2) void gemm_out_kernel(
    const short* __restrict__ A, const short* __restrict__ BTm,
    const float* __restrict__ bias, float* __restrict__ Cout) {
  GEMM_MAIN_LOOP(A, BTm)
#pragma unroll
  for (int i = 0; i < 4; ++i) {
#pragma unroll
    for (int j = 0; j < 4; ++j) {
#pragma unroll
      for (int r = 0; r < 4; ++r) {
        const int grow = rowBase + wm * 64 + i * 16 + g * 4 + r;
        const int gcol = colBase + wn * 64 + j * 16 + c15;
        Cout[(size_t)grow * 1024 + gcol] = acc[i][j][r] + bias[gcol];
      }
    }
  }
}

// ---------------- flash attention v9 ----------------
// v8b + split K/V waits: STAGE order [K,K,V,V]; tile top waits vmcnt(2)
// (K landed, V in flight through QK^T+softmax), V-wait deferred to just
// before PV (vmcnt(4) steady = leaves stage(t+1) in flight). Epilogue
// packs pairs into u32 stores.
__global__ __launch_bounds__(256, 4) void attn_kernel(
    const short* __restrict__ Qg, const short* __restrict__ Kg,
    const short* __restrict__ Vtg, short* __restrict__ ctx) {
  __shared__ short Ks[2][64 * 64];
  __shared__ short VTs[2][64 * 64];

  const int tid = threadIdx.x;
  const int lane = tid & 63;
  const int w = tid >> 6;
  const int l5 = lane >> 5;
  const int c31 = lane & 31;
  // XCD-aware decode of 1D block id (bijective on [0,1024))
  const int lid = blockIdx.x;
  const int bh = (lid >> 7) * 8 + (lid & 7);
  const int qbase = ((lid >> 3) & 15) * 128;
  const int b = bh >> 4, h = bh & 15;

  const short* Qp = Qg + (size_t)bh * TSEQ * DK;
  const short* Kp = Kg + (size_t)bh * TSEQ * DK;
  const short* Vtp = Vtg + (size_t)bh * DK * TSEQ;

  const int qrow = qbase + w * 32 + c31;

  bf16x8 qf[4];
#pragma unroll
  for (int kd = 0; kd < 4; ++kd)
    qf[kd] = *reinterpret_cast<const bf16x8*>(Qp + (size_t)qrow * DK + kd * 16 + l5 * 8);

  f32x16 o0, o1;
#pragma unroll
  for (int r = 0; r < 16; ++r) { o0[r] = 0.f; o1[r] = 0.f; }
  float l_s = 0.f;

  f32x16 z16;
#pragma unroll
  for (int r = 0; r < 16; ++r) z16[r] = 0.f;

  const int srow = w * 8 + (lane >> 3);
  const int soff = ((lane & 7) ^ (lane >> 3) ^ (w & 3)) * 8;
  const int swz = (((c31 & 7) ^ (c31 >> 3)) << 4);

  int offA[4];
#pragma unroll
  for (int kd = 0; kd < 4; ++kd)
    offA[kd] = c31 * 64 + ((((kd * 32 + l5 * 16)) ^ swz) >> 1);

// STAGE order: K first, then V (FIFO basis for the split waits)
#define STAGE(T, SLOT) do {                                                          \
    const int kt_ = (T) * 64;                                                        \
    _Pragma("unroll")                                                                \
    for (int c = 0; c < 2; ++c) {                                                    \
      const int row_ = c * 32 + srow;                                                \
      gl_lds16(Kp + (size_t)(kt_ + row_) * DK + soff, &Ks[SLOT][(c * 4 + w) * 512]); \
    }                                                                                \
    _Pragma("unroll")                                                                \
    for (int c = 0; c < 2; ++c) {                                                    \
      const int row_ = c * 32 + srow;                                                \
      gl_lds16(Vtp + (size_t)row_ * TSEQ + kt_ + soff, &VTs[SLOT][(c * 4 + w) * 512]); \
    }                                                                                \
  } while (0)

#define BODY(T, SLOT, PREFETCH) do {                                                 \
    asm volatile("s_waitcnt vmcnt(2)" ::: "memory");   /* K(t) landed */             \
    __builtin_amdgcn_s_barrier();                                                    \
    __builtin_amdgcn_sched_barrier(0);                                               \
    if (PREFETCH) STAGE((T) + 1, (SLOT) ^ 1);                                        \
    const short* ksb = &Ks[SLOT][0];                                                 \
    const short* vtb = &VTs[SLOT][0];                                                \
    __builtin_amdgcn_s_setprio(1);                                                   \
    const bf16x8 kf0a = *reinterpret_cast<const bf16x8*>(ksb + offA[0]);             \
    const bf16x8 kf1a = *reinterpret_cast<const bf16x8*>(ksb + 2048 + offA[0]);      \
    f32x16 s0 = __builtin_amdgcn_mfma_f32_32x32x16_bf16(kf0a, qf[0], z16, 0, 0, 0);  \
    f32x16 s1 = __builtin_amdgcn_mfma_f32_32x32x16_bf16(kf1a, qf[0], z16, 0, 0, 0);  \
    _Pragma("unroll")                                                                \
    for (int kd = 1; kd < 4; ++kd) {                                                 \
      const bf16x8 kf0 = *reinterpret_cast<const bf16x8*>(ksb + offA[kd]);           \
      const bf16x8 kf1 = *reinterpret_cast<const bf16x8*>(ksb + 2048 + offA[kd]);    \
      s0 = __builtin_amdgcn_mfma_f32_32x32x16_bf16(kf0, qf[kd], s0, 0, 0, 0);        \
      s1 = __builtin_amdgcn_mfma_f32_32x32x16_bf16(kf1, qf[kd], s1, 0, 0, 0);        \
    }                                                                                \
    __builtin_amdgcn_s_setprio(0);                                                   \
    float p0 = 0.f, p1 = 0.f, p2 = 0.f, p3 = 0.f;                                    \
    _Pragma("unroll")                                                                \
    for (int r = 0; r < 16; r += 4) {                                                \
      s0[r] = __builtin_amdgcn_exp2f(s0[r]);                                         \
      s0[r + 1] = __builtin_amdgcn_exp2f(s0[r + 1]);                                 \
      s0[r + 2] = __builtin_amdgcn_exp2f(s0[r + 2]);                                 \
      s0[r + 3] = __builtin_amdgcn_exp2f(s0[r + 3]);                                 \
      p0 += s0[r]; p1 += s0[r + 1]; p2 += s0[r + 2]; p3 += s0[r + 3];                \
    }                                                                                \
    _Pragma("unroll")                                                                \
    for (int r = 0; r < 16; r += 4) {                                                \
      s1[r] = __builtin_amdgcn_exp2f(s1[r]);                                         \
      s1[r + 1] = __builtin_amdgcn_exp2f(s1[r + 1]);                                 \
      s1[r + 2] = __builtin_amdgcn_exp2f(s1[r + 2]);                                 \
      s1[r + 3] = __builtin_amdgcn_exp2f(s1[r + 3]);                                 \
      p0 += s1[r]; p1 += s1[r + 1]; p2 += s1[r + 2]; p3 += s1[r + 3];                \
    }                                                                                \
    l_s += (p0 + p1) + (p2 + p3);                                                    \
    uint32_t wa[8], wb[8];                                                           \
    _Pragma("unroll")                                                                \
    for (int t2 = 0; t2 < 8; ++t2) {                                                 \
      wa[t2] = cvt_pk(s0[2 * t2], s0[2 * t2 + 1]);                                   \
      wb[t2] = cvt_pk(s1[2 * t2], s1[2 * t2 + 1]);                                   \
    }                                                                                \
    permswap(wa[0], wa[2]); permswap(wa[1], wa[3]);                                  \
    permswap(wa[4], wa[6]); permswap(wa[5], wa[7]);                                  \
    permswap(wb[0], wb[2]); permswap(wb[1], wb[3]);                                  \
    permswap(wb[4], wb[6]); permswap(wb[5], wb[7]);                                  \
    bf16x8 pf[4];                                                                    \
    {                                                                                \
      union { uint32_t u[4]; bf16x8 v; } fr;                                         \
      fr.u[0] = wa[0]; fr.u[1] = wa[1]; fr.u[2] = wa[2]; fr.u[3] = wa[3]; pf[0] = fr.v; \
      fr.u[0] = wa[4]; fr.u[1] = wa[5]; fr.u[2] = wa[6]; fr.u[3] = wa[7]; pf[1] = fr.v; \
      fr.u[0] = wb[0]; fr.u[1] = wb[1]; fr.u[2] = wb[2]; fr.u[3] = wb[3]; pf[2] = fr.v; \
      fr.u[0] = wb[4]; fr.u[1] = wb[5]; fr.u[2] = wb[6]; fr.u[3] = wb[7]; pf[3] = fr.v; \
    }                                                                                \
    asm volatile("s_waitcnt vmcnt(%0)" :: "i"((PREFETCH) ? 4 : 0) : "memory");       \
    __builtin_amdgcn_s_setprio(1);                                                   \
    _Pragma("unroll")                                                                \
    for (int ks = 0; ks < 4; ++ks) {                                                 \
      const bf16x8 vf0 = *reinterpret_cast<const bf16x8*>(vtb + offA[ks]);           \
      const bf16x8 vf1 = *reinterpret_cast<const bf16x8*>(vtb + 2048 + offA[ks]);    \
      o0 = __builtin_amdgcn_mfma_f32_32x32x16_bf16(vf0, pf[ks], o0, 0, 0, 0);        \
      o1 = __builtin_amdgcn_mfma_f32_32x32x16_bf16(vf1, pf[ks], o1, 0, 0, 0);        \
    }                                                                                \
    __builtin_amdgcn_s_setprio(0);                                                   \
  } while (0)

  STAGE(0, 0);
  for (int t = 0; t < 30; t += 2) {
    BODY(t, 0, true);
    BODY(t + 1, 1, true);
  }
  BODY(30, 0, true);
  BODY(31, 1, false);

#undef STAGE
#undef BODY

  l_s += __shfl_xor(l_s, 32, 64);

  // epilogue: packed u32 stores (pairs r, r+1 -> d, d+1; d even for even r)
  const float inv = 1.0f / l_s;
  short* crow = ctx + ((size_t)b * TSEQ + qrow) * D_MODEL + h * 64;
#pragma unroll
  for (int r = 0; r < 16; r += 2) {
    const int d = (r & 3) + 8 * (r >> 2) + 4 * l5;
    *reinterpret_cast<uint32_t*>(&crow[d]) = cvt_pk(o0[r] * inv, o0[r + 1] * inv);
    *reinterpret_cast<uint32_t*>(&crow[32 + d]) = cvt_pk(o1[r] * inv, o1[r + 1] * inv);
  }
}

extern "C" void kernel_launch(void* const* d_in, const int* in_sizes, int n_in,
                              void* d_out, int out_size, void* d_ws, size_t ws_size,
                              hipStream_t stream) {
  const float* x  = (const float*)d_in[0];
  const float* Wq = (const float*)d_in[1];
  const float* bq = (const float*)d_in[2];
  const float* Wk = (const float*)d_in[3];
  const float* bk = (const float*)d_in[4];
  const float* Wv = (const float*)d_in[5];
  const float* bv = (const float*)d_in[6];
  const float* Wo = (const float*)d_in[7];
  const float* bo = (const float*)d_in[8];
  float* out = (float*)d_out;

  short* xb   = (short*)d_ws;                       // 8192*1024 bf16 (reused as ctx)
  short* WqT  = xb + (size_t)MROWS * D_MODEL;       // WqT/WkT/WvT contiguous: fused B
  short* WkT  = WqT + (size_t)D_MODEL * D_MODEL;
  short* WvT  = WkT + (size_t)D_MODEL * D_MODEL;
  short* WoT  = WvT + (size_t)D_MODEL * D_MODEL;
  short* Qb   = WoT + (size_t)D_MODEL * D_MODEL;
  short* Kb   = Qb + (size_t)MROWS * D_MODEL;
  short* Vtb  = Kb + (size_t)MROWS * D_MODEL;       // V^T layout [B,H,dk,T]
  short* ctxb = xb;                                 // xb dead after QKV projection

  const float CL = 0.1803368801111204f;             // 0.125 * log2(e), folded into Q

  prep_kernel<<<dim3(32, 32, 8), dim3(32, 8), 0, stream>>>(
      x, xb, Wq, Wk, Wv, Wo, WqT, WkT, WvT, WoT);

  gemm_qkv_kernel<<<dim3(MROWS / 128, 3 * D_MODEL / 128), 256, 0, stream>>>(
      xb, WqT, bq, bk, bv, Qb, Kb, Vtb, CL);

  attn_kernel<<<1024, 256, 0, stream>>>(Qb, Kb, Vtb, ctxb);

  gemm_out_kernel<<<dim3(MROWS / 128, D_MODEL / 128), 256, 0, stream>>>(ctxb, WoT, bo, out);
}